// Round 4
// baseline (882.719 us; speedup 1.0000x reference)
//
#include <hip/hip_runtime.h>

// Problem constants (from reference)
#define NB      128   // batch
#define ND      8     // input dims
#define NK      8     // regimes
#define TLEN    512
#define NSTEPS  496   // T - CAPACITY
#define QMAX    510   // last stream position = 495 + 15

__device__ __forceinline__ float elur(float x) {
    return x > 0.f ? x : expf(x) - 1.f;   // elu; |err| vs expm1 << threshold
}

// 32-term dot: p is an LDS vector (32 floats, 16B aligned), w is a register array
__device__ __forceinline__ float ldot32(const float* p, const float* w) {
    const float4* q4 = (const float4*)p;
    float a0 = 0.f, a1 = 0.f, a2 = 0.f, a3 = 0.f;
    #pragma unroll
    for (int i = 0; i < 8; ++i) {
        float4 v = q4[i];
        a0 = fmaf(w[4*i+0], v.x, a0);
        a1 = fmaf(w[4*i+1], v.y, a1);
        a2 = fmaf(w[4*i+2], v.z, a2);
        a3 = fmaf(w[4*i+3], v.w, a3);
    }
    return (a0 + a1) + (a2 + a3);
}

// 8-term dot on one xcol column (8 floats, 16B aligned)
__device__ __forceinline__ float ldot8(const float* p, const float* w) {
    const float4* q4 = (const float4*)p;
    float4 a = q4[0], b = q4[1];
    float s0 = fmaf(w[0], a.x, fmaf(w[1], a.y, 0.f));
    float s1 = fmaf(w[2], a.z, fmaf(w[3], a.w, 0.f));
    float s2 = fmaf(w[4], b.x, fmaf(w[5], b.y, 0.f));
    float s3 = fmaf(w[6], b.z, fmaf(w[7], b.w, 0.f));
    return (s0 + s1) + (s2 + s3);
}

// One scan step. qv: runtime stream position; S1/S2/S3: compile-time pipe slots;
// DO_OUT: compile-time flag (1 for q >= 15).
#define STEP(qv, S1, S2, S3, DO_OUT)                                              \
  {                                                                               \
    const int q_ = (qv);                                                          \
    /* layer 0: x-part was parked in X0 last step; z-part on critical path */     \
    float dz = 0.f;                                                               \
    _Pragma("unroll")                                                             \
    for (int k = 0; k < 8; ++k) dz = fmaf(wz[k], zp[k], dz);                      \
    _Pragma("unroll")                                                             \
    for (int k = 0; k < 8; ++k) dz = fmaf(wz[8 + k], zc[k], dz);                  \
    float o0 = elur(X0 + dz);                                                     \
    bc0[lane] = o0;                                                               \
    /* park x-part for step q_+1 (independent of recurrence) */                   \
    {                                                                             \
      float xp = ldot8(&xcol[q_ + tap][0], wxr);                                  \
      X0 = xp + __shfl_down(xp, 32) + b0r;                                        \
    }                                                                             \
    float d1 = ldot32(bc0, w1r);                                                  \
    float o1 = elur(d1 + P1[S1]);                                                 \
    P1[S1] = b1r + __shfl_down(d1, 32);                                           \
    bc1[lane] = o1;                                                               \
    float d2 = ldot32(bc1, w2r);                                                  \
    float o2 = elur(d2 + P2[S2]);                                                 \
    P2[S2] = b2r + __shfl_down(d2, 32);                                           \
    bc2[lane] = o2;                                                               \
    float d3 = ldot32(bc2, w3r);                                                  \
    float a3m = elur(d3 + P3[S3]);                                                \
    P3[S3] = b3r + __shfl_down(d3, 32);                                           \
    if (DO_OUT) {                                                                 \
      float A0 = __shfl(a3m, 0), A1 = __shfl(a3m, 1), A2 = __shfl(a3m, 2),        \
            A3v = __shfl(a3m, 3), A4 = __shfl(a3m, 4), A5 = __shfl(a3m, 5),       \
            A6 = __shfl(a3m, 6), A7 = __shfl(a3m, 7);                             \
      float mx = fmaxf(fmaxf(fmaxf(A0, A1), fmaxf(A2, A3v)),                      \
                       fmaxf(fmaxf(A4, A5), fmaxf(A6, A7)));                      \
      float E0 = expf(A0 - mx), E1 = expf(A1 - mx), E2 = expf(A2 - mx),           \
            E3 = expf(A3v - mx), E4 = expf(A4 - mx), E5 = expf(A5 - mx),          \
            E6 = expf(A6 - mx), E7 = expf(A7 - mx);                               \
      float se = ((E0 + E1) + (E2 + E3)) + ((E4 + E5) + (E6 + E7));               \
      float lse = logf(se);                                                       \
      const int sidx = q_ - 15;                                                   \
      const float4* gp = (const float4*)&gls[sidx * 8];                           \
      float4 ga = gp[0], gb = gp[1];                                              \
      float T0 = (A0 - mx - lse + ga.x) * tinv, T1 = (A1 - mx - lse + ga.y) * tinv, \
            T2 = (A2 - mx - lse + ga.z) * tinv, T3 = (A3v - mx - lse + ga.w) * tinv,\
            T4 = (A4 - mx - lse + gb.x) * tinv, T5 = (A5 - mx - lse + gb.y) * tinv, \
            T6 = (A6 - mx - lse + gb.z) * tinv, T7 = (A7 - mx - lse + gb.w) * tinv; \
      float m2 = fmaxf(fmaxf(fmaxf(T0, T1), fmaxf(T2, T3)),                       \
                       fmaxf(fmaxf(T4, T5), fmaxf(T6, T7)));                      \
      float F0 = expf(T0 - m2), F1 = expf(T1 - m2), F2 = expf(T2 - m2),           \
            F3 = expf(T3 - m2), F4 = expf(T4 - m2), F5 = expf(T5 - m2),           \
            F6 = expf(T6 - m2), F7 = expf(T7 - m2);                               \
      float s2 = ((F0 + F1) + (F2 + F3)) + ((F4 + F5) + (F6 + F7));               \
      float r2 = 1.f / s2;                                                        \
      _Pragma("unroll")                                                           \
      for (int k = 0; k < 8; ++k) zp[k] = zc[k];                                  \
      zc[0] = F0 * r2; zc[1] = F1 * r2; zc[2] = F2 * r2; zc[3] = F3 * r2;         \
      zc[4] = F4 * r2; zc[5] = F5 * r2; zc[6] = F6 * r2; zc[7] = F7 * r2;         \
      if (lane < 8) {                                                             \
        float lqm = a3m - mx - lse;                                               \
        float gm  = gls[sidx * 8 + lane];                                         \
        float ym  = expf((lqm + gm) * tinv - m2) * r2;                            \
        outg[zoff + lane * TLEN + q_ + 1]  = ym;                                  \
        outg[qoff + lane * NSTEPS + sidx]  = lqm;                                 \
      }                                                                           \
    }                                                                             \
  }

__global__ __launch_bounds__(64, 1)
void regime_scan_kernel(const float* __restrict__ xg,
                        const float* __restrict__ tempg,
                        const float* __restrict__ ug,
                        const float* __restrict__ w0g,
                        const float* __restrict__ b0g,
                        const float* __restrict__ w1g,
                        const float* __restrict__ b1g,
                        const float* __restrict__ w2g,
                        const float* __restrict__ b2g,
                        const float* __restrict__ w3g,
                        const float* __restrict__ b3g,
                        float* __restrict__ outg)
{
    __shared__ __align__(16) float xcol[527][8];     // padded x stream columns (16.9 KB)
    __shared__ __align__(16) float gls[NSTEPS * NK]; // Gumbel noise (15.9 KB)
    __shared__ __align__(16) float bc0[64], bc1[64], bc2[64]; // broadcast slots

    const int lane = threadIdx.x;
    const int b    = blockIdx.x;
    const int c    = lane & 31;            // channel owned (layers 0-2)
    const int o3   = lane & 7;             // layer-3 output owned
    const int tap  = (lane < 32) ? 1 : 0;  // low half: new tap; high half: old tap

    // ---- per-lane weights -> registers ----
    float wz[16];                           // layer0 z-part, both taps (all lanes)
    #pragma unroll
    for (int k = 0; k < 8; ++k) {
        wz[k]     = w0g[c * 32 + (8 + k) * 2 + 0];   // old tap -> zp
        wz[8 + k] = w0g[c * 32 + (8 + k) * 2 + 1];   // new tap -> zc
    }
    float wxr[8];                           // layer0 x-part, tap-split
    #pragma unroll
    for (int d = 0; d < 8; ++d) wxr[d] = w0g[c * 32 + d * 2 + tap];
    float w1r[32], w2r[32], w3r[32];        // tap-split across wave halves
    #pragma unroll
    for (int i = 0; i < 32; ++i) {
        w1r[i] = w1g[c * 64 + i * 2 + tap];
        w2r[i] = w2g[c * 64 + i * 2 + tap];
        w3r[i] = w3g[o3 * 64 + i * 2 + tap];
    }
    const float b0r  = b0g[c];
    const float b1r  = b1g[c];
    const float b2r  = b2g[c];
    const float b3r  = b3g[o3];
    const float tinv = 1.0f / tempg[0];

    // ---- prologue: x columns into LDS ----
    if (lane < 15) {
        #pragma unroll
        for (int d = 0; d < ND; ++d) xcol[lane][d] = 0.f;
    }
    const float* xb = xg + b * (ND * TLEN);
    for (int t = lane; t < TLEN; t += 64) {
        #pragma unroll
        for (int d = 0; d < ND; ++d) xcol[15 + t][d] = xb[d * TLEN + t];
    }

    // ---- prologue: Gumbel noise ----
    for (int idx = lane; idx < NSTEPS * NK; idx += 64) {
        int s = idx >> 3, k = idx & 7;
        float uu = ug[s * (NB * NK) + b * NK + k];
        gls[idx] = -logf(-logf(uu + 1e-10f) + 1e-10f);
    }

    // ---- z_all[:, :, 0:16] = 0 ----
    const int zoff = b * (NK * TLEN);
    const int qoff = NB * NK * TLEN + b * (NK * NSTEPS);
    for (int idx = lane; idx < NK * 16; idx += 64) {
        outg[zoff + (idx >> 4) * TLEN + (idx & 15)] = 0.f;
    }

    // ---- state init ----
    float zp[8], zc[8];
    #pragma unroll
    for (int k = 0; k < 8; ++k) { zp[k] = 0.f; zc[k] = 0.f; }
    float P1[2] = { b1r, b1r };
    float P2[4] = { b2r, b2r, b2r, b2r };
    float P3[8];
    #pragma unroll
    for (int k = 0; k < 8; ++k) P3[k] = b3r;

    // X0 = layer0 x-part + b0 for q=1 (new tap on xcol[1], old tap on xcol[0])
    float X0;
    {
        float xp = ldot8(&xcol[tap][0], wxr);
        X0 = xp + __shfl_down(xp, 32) + b0r;
    }

    // ---- warmup q=1..14 (fully unrolled; no outputs, no z update) ----
    #pragma unroll
    for (int q = 1; q <= 14; ++q) STEP(q, q & 1, q & 3, q & 7, 0);

    // ---- main loop q=15..510, unrolled by 8 (static pipe-register rotation) ----
    for (int qb = 15; qb <= 503; qb += 8) {
        #pragma unroll
        for (int u = 0; u < 8; ++u) {
            STEP(qb + u, (15 + u) & 1, (15 + u) & 3, (15 + u) & 7, 1);
        }
    }
}

extern "C" void kernel_launch(void* const* d_in, const int* in_sizes, int n_in,
                              void* d_out, int out_size, void* d_ws, size_t ws_size,
                              hipStream_t stream) {
    (void)in_sizes; (void)n_in; (void)out_size; (void)d_ws; (void)ws_size;
    regime_scan_kernel<<<dim3(NB), dim3(64), 0, stream>>>(
        (const float*)d_in[0],   // x
        (const float*)d_in[1],   // temp
        (const float*)d_in[2],   // u
        (const float*)d_in[3],   // w0
        (const float*)d_in[4],   // b0
        (const float*)d_in[5],   // w1
        (const float*)d_in[6],   // b1
        (const float*)d_in[7],   // w2
        (const float*)d_in[8],   // b2
        (const float*)d_in[9],   // w3
        (const float*)d_in[10],  // b3
        (float*)d_out);
}

// Round 5
// 646.918 us; speedup vs baseline: 1.3645x; 1.3645x over previous
//
#include <hip/hip_runtime.h>

// Problem constants (from reference)
#define NB      128   // batch
#define ND      8     // input dims
#define NK      8     // regimes
#define TLEN    512
#define NSTEPS  496   // T - CAPACITY
#define QMAX    510   // last stream position = 495 + 15

__device__ __forceinline__ float fexp(float x) { return __expf(x); }   // v_exp_f32
__device__ __forceinline__ float flog(float x) { return __logf(x); }   // v_log_f32
__device__ __forceinline__ float frcp(float x) { return __builtin_amdgcn_rcpf(x); }

__device__ __forceinline__ float elur(float x) {
    return x > 0.f ? x : fexp(x) - 1.f;   // elu; |err| vs libm expm1 << threshold
}

// 32-term dot: p is an LDS vector (32 floats, 16B aligned), w is a register array
__device__ __forceinline__ float ldot32(const float* p, const float* w) {
    const float4* q4 = (const float4*)p;
    float a0 = 0.f, a1 = 0.f, a2 = 0.f, a3 = 0.f;
    #pragma unroll
    for (int i = 0; i < 8; ++i) {
        float4 v = q4[i];
        a0 = fmaf(w[4*i+0], v.x, a0);
        a1 = fmaf(w[4*i+1], v.y, a1);
        a2 = fmaf(w[4*i+2], v.z, a2);
        a3 = fmaf(w[4*i+3], v.w, a3);
    }
    return (a0 + a1) + (a2 + a3);
}

// 8-term dot on one xcol column (8 floats, 16B aligned)
__device__ __forceinline__ float ldot8(const float* p, const float* w) {
    const float4* q4 = (const float4*)p;
    float4 a = q4[0], b = q4[1];
    float s0 = fmaf(w[0], a.x, fmaf(w[1], a.y, 0.f));
    float s1 = fmaf(w[2], a.z, fmaf(w[3], a.w, 0.f));
    float s2 = fmaf(w[4], b.x, fmaf(w[5], b.y, 0.f));
    float s3 = fmaf(w[6], b.z, fmaf(w[7], b.w, 0.f));
    return (s0 + s1) + (s2 + s3);
}

// One scan step. qv: runtime position; S1/S2/S3: compile-time pipe slots;
// ZP/ZC: z-state register arrays (y[s-2] / y[s-1]); new y overwrites ZP.
// DO_OUT: compile-time (1 for q >= 15).
#define STEP(qv, S1, S2, S3, ZP, ZC, DO_OUT)                                      \
  {                                                                               \
    const int q_ = (qv);                                                          \
    /* layer 0: x-part was parked in X0 last step; z-part: 4 parallel chains */   \
    float za0 = 0.f, za1 = 0.f, za2 = 0.f, za3 = 0.f;                             \
    _Pragma("unroll")                                                             \
    for (int k = 0; k < 4; ++k) {                                                 \
      za0 = fmaf(wz[2*k],       ZP[2*k],   za0);                                  \
      za1 = fmaf(wz[2*k+1],     ZP[2*k+1], za1);                                  \
      za2 = fmaf(wz[8 + 2*k],   ZC[2*k],   za2);                                  \
      za3 = fmaf(wz[8 + 2*k+1], ZC[2*k+1], za3);                                  \
    }                                                                             \
    float o0 = elur(X0 + ((za0 + za1) + (za2 + za3)));                            \
    bc0[lane] = o0;                                                               \
    /* park x-part for step q_+1 (independent of recurrence) */                   \
    {                                                                             \
      float xp = ldot8(&xcol[q_ + tap][0], wxr);                                  \
      X0 = xp + __shfl_down(xp, 32) + b0r;                                        \
    }                                                                             \
    float d1 = ldot32(bc0, w1r);                                                  \
    float o1 = elur(d1 + P1[S1]);                                                 \
    P1[S1] = b1r + __shfl_down(d1, 32);                                           \
    bc1[lane] = o1;                                                               \
    float d2 = ldot32(bc1, w2r);                                                  \
    float o2 = elur(d2 + P2[S2]);                                                 \
    P2[S2] = b2r + __shfl_down(d2, 32);                                           \
    bc2[lane] = o2;                                                               \
    float d3 = ldot32(bc2, w3r);                                                  \
    float a3m = elur(d3 + P3[S3]);                                                \
    P3[S3] = b3r + __shfl_down(d3, 32);                                           \
    if (DO_OUT) {                                                                 \
      float A0 = __shfl(a3m, 0), A1 = __shfl(a3m, 1), A2 = __shfl(a3m, 2),        \
            A3v = __shfl(a3m, 3), A4 = __shfl(a3m, 4), A5 = __shfl(a3m, 5),       \
            A6 = __shfl(a3m, 6), A7 = __shfl(a3m, 7);                             \
      const int sidx = q_ - 15;                                                   \
      const float4* gp = (const float4*)&gls[sidx * 8];                           \
      float4 ga = gp[0], gb = gp[1];                                              \
      /* gumbel-softmax: softmax((a3+g)/t) — mx/lse cancel (shift-invariant) */   \
      float T0 = (A0 + ga.x) * tinv, T1 = (A1 + ga.y) * tinv,                     \
            T2 = (A2 + ga.z) * tinv, T3 = (A3v + ga.w) * tinv,                    \
            T4 = (A4 + gb.x) * tinv, T5 = (A5 + gb.y) * tinv,                     \
            T6 = (A6 + gb.z) * tinv, T7 = (A7 + gb.w) * tinv;                     \
      float m2 = fmaxf(fmaxf(fmaxf(T0, T1), fmaxf(T2, T3)),                       \
                       fmaxf(fmaxf(T4, T5), fmaxf(T6, T7)));                      \
      float F0 = fexp(T0 - m2), F1 = fexp(T1 - m2), F2 = fexp(T2 - m2),           \
            F3 = fexp(T3 - m2), F4 = fexp(T4 - m2), F5 = fexp(T5 - m2),           \
            F6 = fexp(T6 - m2), F7 = fexp(T7 - m2);                               \
      float s2 = ((F0 + F1) + (F2 + F3)) + ((F4 + F5) + (F6 + F7));               \
      float r2 = frcp(s2);                                                        \
      ZP[0] = F0 * r2; ZP[1] = F1 * r2; ZP[2] = F2 * r2; ZP[3] = F3 * r2;         \
      ZP[4] = F4 * r2; ZP[5] = F5 * r2; ZP[6] = F6 * r2; ZP[7] = F7 * r2;         \
      /* log-softmax output (off the recurrence path) */                          \
      float mx = fmaxf(fmaxf(fmaxf(A0, A1), fmaxf(A2, A3v)),                      \
                       fmaxf(fmaxf(A4, A5), fmaxf(A6, A7)));                      \
      float E0 = fexp(A0 - mx), E1 = fexp(A1 - mx), E2 = fexp(A2 - mx),           \
            E3 = fexp(A3v - mx), E4 = fexp(A4 - mx), E5 = fexp(A5 - mx),          \
            E6 = fexp(A6 - mx), E7 = fexp(A7 - mx);                               \
      float se = ((E0 + E1) + (E2 + E3)) + ((E4 + E5) + (E6 + E7));               \
      float lse = mx + flog(se);                                                  \
      if (lane < 8) {                                                             \
        float gm  = gls[sidx * 8 + lane];                                         \
        float ym  = fexp((a3m + gm) * tinv - m2) * r2;                            \
        outg[zoff + lane * TLEN + q_ + 1]  = ym;                                  \
        outg[qoff + lane * NSTEPS + sidx]  = a3m - lse;                           \
      }                                                                           \
    }                                                                             \
  }

__global__ __launch_bounds__(64, 1)
void regime_scan_kernel(const float* __restrict__ xg,
                        const float* __restrict__ tempg,
                        const float* __restrict__ ug,
                        const float* __restrict__ w0g,
                        const float* __restrict__ b0g,
                        const float* __restrict__ w1g,
                        const float* __restrict__ b1g,
                        const float* __restrict__ w2g,
                        const float* __restrict__ b2g,
                        const float* __restrict__ w3g,
                        const float* __restrict__ b3g,
                        float* __restrict__ outg)
{
    __shared__ __align__(16) float xcol[527][8];     // padded x stream columns (16.9 KB)
    __shared__ __align__(16) float gls[NSTEPS * NK]; // Gumbel noise (15.9 KB)
    __shared__ __align__(16) float bc0[64], bc1[64], bc2[64]; // broadcast slots

    const int lane = threadIdx.x;
    const int b    = blockIdx.x;
    const int c    = lane & 31;            // channel owned (layers 0-2)
    const int o3   = lane & 7;             // layer-3 output owned
    const int tap  = (lane < 32) ? 1 : 0;  // low half: new tap; high half: old tap

    // ---- per-lane weights -> registers ----
    float wz[16];                           // layer0 z-part, both taps (all lanes)
    #pragma unroll
    for (int k = 0; k < 8; ++k) {
        wz[k]     = w0g[c * 32 + (8 + k) * 2 + 0];   // old tap -> zp
        wz[8 + k] = w0g[c * 32 + (8 + k) * 2 + 1];   // new tap -> zc
    }
    float wxr[8];                           // layer0 x-part, tap-split
    #pragma unroll
    for (int d = 0; d < 8; ++d) wxr[d] = w0g[c * 32 + d * 2 + tap];
    float w1r[32], w2r[32], w3r[32];        // tap-split across wave halves
    #pragma unroll
    for (int i = 0; i < 32; ++i) {
        w1r[i] = w1g[c * 64 + i * 2 + tap];
        w2r[i] = w2g[c * 64 + i * 2 + tap];
        w3r[i] = w3g[o3 * 64 + i * 2 + tap];
    }
    const float b0r  = b0g[c];
    const float b1r  = b1g[c];
    const float b2r  = b2g[c];
    const float b3r  = b3g[o3];
    const float tinv = frcp(tempg[0]);

    // ---- prologue: x columns into LDS ----
    if (lane < 15) {
        #pragma unroll
        for (int d = 0; d < ND; ++d) xcol[lane][d] = 0.f;
    }
    const float* xb = xg + b * (ND * TLEN);
    for (int t = lane; t < TLEN; t += 64) {
        #pragma unroll
        for (int d = 0; d < ND; ++d) xcol[15 + t][d] = xb[d * TLEN + t];
    }

    // ---- prologue: Gumbel noise ----
    for (int idx = lane; idx < NSTEPS * NK; idx += 64) {
        int s = idx >> 3, k = idx & 7;
        float uu = ug[s * (NB * NK) + b * NK + k];
        gls[idx] = -flog(-flog(uu + 1e-10f) + 1e-10f);
    }

    // ---- z_all[:, :, 0:16] = 0 ----
    const int zoff = b * (NK * TLEN);
    const int qoff = NB * NK * TLEN + b * (NK * NSTEPS);
    for (int idx = lane; idx < NK * 16; idx += 64) {
        outg[zoff + (idx >> 4) * TLEN + (idx & 15)] = 0.f;
    }

    // ---- state init ----
    float zA[8], zB[8];
    #pragma unroll
    for (int k = 0; k < 8; ++k) { zA[k] = 0.f; zB[k] = 0.f; }
    float P1[2] = { b1r, b1r };
    float P2[4] = { b2r, b2r, b2r, b2r };
    float P3[8];
    #pragma unroll
    for (int k = 0; k < 8; ++k) P3[k] = b3r;

    // X0 = layer0 x-part + b0 for q=1
    float X0;
    {
        float xp = ldot8(&xcol[tap][0], wxr);
        X0 = xp + __shfl_down(xp, 32) + b0r;
    }

    // ---- warmup q=1..14 (no outputs, z stays zero) ----
    #pragma unroll
    for (int q = 1; q <= 14; ++q) STEP(q, q & 1, q & 3, q & 7, zA, zB, 0);

    // ---- main loop q=15..510, unrolled by 8; z double-buffer by parity ----
    // step s: zp=y[s-2], zc=y[s-1]; writes y[s] over zp; roles swap each step.
    for (int qb = 15; qb <= 503; qb += 8) {
        #pragma unroll
        for (int u = 0; u < 8; u += 2) {
            STEP(qb + u,     (15 + u) & 1, (15 + u) & 3, (15 + u) & 7, zA, zB, 1);
            STEP(qb + u + 1, (16 + u) & 1, (16 + u) & 3, (16 + u) & 7, zB, zA, 1);
        }
    }
}

extern "C" void kernel_launch(void* const* d_in, const int* in_sizes, int n_in,
                              void* d_out, int out_size, void* d_ws, size_t ws_size,
                              hipStream_t stream) {
    (void)in_sizes; (void)n_in; (void)out_size; (void)d_ws; (void)ws_size;
    regime_scan_kernel<<<dim3(NB), dim3(64), 0, stream>>>(
        (const float*)d_in[0],   // x
        (const float*)d_in[1],   // temp
        (const float*)d_in[2],   // u
        (const float*)d_in[3],   // w0
        (const float*)d_in[4],   // b0
        (const float*)d_in[5],   // w1
        (const float*)d_in[6],   // b1
        (const float*)d_in[7],   // w2
        (const float*)d_in[8],   // b2
        (const float*)d_in[9],   // w3
        (const float*)d_in[10],  // b3
        (float*)d_out);
}

// Round 8
// 542.559 us; speedup vs baseline: 1.6270x; 1.1923x over previous
//
#include <hip/hip_runtime.h>

// Problem constants (from reference)
#define NB      128
#define ND      8
#define NK      8
#define TLEN    512
#define NSTEPS  496
#define QMAX    510

__device__ __forceinline__ float fexp(float x) { return __expf(x); }
__device__ __forceinline__ float flog(float x) { return __logf(x); }
__device__ __forceinline__ float frcp(float x) { return __builtin_amdgcn_rcpf(x); }
__device__ __forceinline__ float elur(float x) { return x > 0.f ? x : fexp(x) - 1.f; }

// DPP helpers: quad_perm[k,k,k,k] and row_ror:4 (cross-quad within 16-lane row;
// valid because channel data is replicated every 8 lanes on lanes 0..31)
#define DPP_QP0(v) __int_as_float(__builtin_amdgcn_mov_dpp(__float_as_int(v), 0x00, 0xF, 0xF, false))
#define DPP_QP1(v) __int_as_float(__builtin_amdgcn_mov_dpp(__float_as_int(v), 0x55, 0xF, 0xF, false))
#define DPP_QP2(v) __int_as_float(__builtin_amdgcn_mov_dpp(__float_as_int(v), 0xAA, 0xF, 0xF, false))
#define DPP_QP3(v) __int_as_float(__builtin_amdgcn_mov_dpp(__float_as_int(v), 0xFF, 0xF, 0xF, false))
#define DPP_ROR4(v) __int_as_float(__builtin_amdgcn_mov_dpp(__float_as_int(v), 0x124, 0xF, 0xF, false))

// 32-term dot, 8 parallel chains (latency ~16 + 12 combine)
__device__ __forceinline__ float ldot32(const float* p, const float* w) {
    const float4* q4 = (const float4*)p;
    float a[8];
    #pragma unroll
    for (int i = 0; i < 8; ++i) {
        float4 v = q4[i];
        float t0 = fmaf(w[4*i+0], v.x, 0.f);
        float t1 = fmaf(w[4*i+1], v.y, 0.f);
        t0 = fmaf(w[4*i+2], v.z, t0);
        t1 = fmaf(w[4*i+3], v.w, t1);
        a[i] = t0 + t1;
    }
    float s0 = (a[0] + a[1]) + (a[2] + a[3]);
    float s1 = (a[4] + a[5]) + (a[6] + a[7]);
    return s0 + s1;
}

__device__ __forceinline__ float ldot8(const float* p, const float* w) {
    const float4* q4 = (const float4*)p;
    float4 a = q4[0], b = q4[1];
    float s0 = fmaf(w[0], a.x, fmaf(w[1], a.y, 0.f));
    float s1 = fmaf(w[2], a.z, fmaf(w[3], a.w, 0.f));
    float s2 = fmaf(w[4], b.x, fmaf(w[5], b.y, 0.f));
    float s3 = fmaf(w[6], b.z, fmaf(w[7], b.w, 0.f));
    return (s0 + s1) + (s2 + s3);
}

// One scan step. ZP = y(q-2) slots (overwritten with y(q)), ZC = y(q-1) slots.
// Slot k on a lane holds channel (k ^ 4p), p = (lane>>2)&1 — DPP parity order.
// ZQ2 pipeline (2-deep): at step q's tail, ZQ2 == wzo.y(q-1) -> old tap for step q+1.
#define STEP(qv, S1, S2, S3, ZP, ZC, DO_OUT)                                      \
  {                                                                               \
    const int q_ = (qv);                                                          \
    /* layer 0 critical: new-tap z-dot only (old-tap folded into XZ) */           \
    float _d0 = fmaf(wzn[0], ZC[0], 0.f);                                         \
    float _d1 = fmaf(wzn[1], ZC[1], 0.f);                                         \
    float _d2 = fmaf(wzn[2], ZC[2], 0.f);                                         \
    float _d3 = fmaf(wzn[3], ZC[3], 0.f);                                         \
    _d0 = fmaf(wzn[4], ZC[4], _d0);                                               \
    _d1 = fmaf(wzn[5], ZC[5], _d1);                                               \
    _d2 = fmaf(wzn[6], ZC[6], _d2);                                               \
    _d3 = fmaf(wzn[7], ZC[7], _d3);                                               \
    float o0 = elur(XZ + ((_d0 + _d1) + (_d2 + _d3)));                            \
    bc0[lane] = o0;                                                               \
    float d1v = ldot32(bc0, w1r);                                                 \
    float o1 = elur(d1v + P1[S1]);                                                \
    P1[S1] = b1r + __shfl_down(d1v, 32);                                          \
    bc1[lane] = o1;                                                               \
    float d2v = ldot32(bc1, w2r);                                                 \
    float o2 = elur(d2v + P2[S2]);                                                \
    P2[S2] = b2r + __shfl_down(d2v, 32);                                          \
    bc2[lane] = o2;                                                               \
    float d3v = ldot32(bc2, w3r);                                                 \
    float a3m = elur(d3v + P3[S3]);                                               \
    P3[S3] = b3r + __shfl_down(d3v, 32);                                          \
    if (DO_OUT) {                                                                 \
      /* DPP broadcast: slot j holds A_{j^4p} */                                  \
      float _t = DPP_ROR4(a3m);                                                   \
      float A0 = DPP_QP0(a3m), A1 = DPP_QP1(a3m), A2 = DPP_QP2(a3m),              \
            A3v = DPP_QP3(a3m);                                                   \
      float A4 = DPP_QP0(_t), A5 = DPP_QP1(_t), A6 = DPP_QP2(_t),                 \
            A7 = DPP_QP3(_t);                                                     \
      const int sidx = q_ - 15;                                                   \
      float T0 = (A0 + GA.x) * tinv, T1 = (A1 + GA.y) * tinv,                     \
            T2 = (A2 + GA.z) * tinv, T3 = (A3v + GA.w) * tinv,                    \
            T4 = (A4 + GB.x) * tinv, T5 = (A5 + GB.y) * tinv,                     \
            T6 = (A6 + GB.z) * tinv, T7 = (A7 + GB.w) * tinv;                     \
      float m2 = fmaxf(fmaxf(fmaxf(T0, T1), fmaxf(T2, T3)),                       \
                       fmaxf(fmaxf(T4, T5), fmaxf(T6, T7)));                      \
      float F0 = fexp(T0 - m2), F1 = fexp(T1 - m2), F2 = fexp(T2 - m2),           \
            F3 = fexp(T3 - m2), F4 = fexp(T4 - m2), F5 = fexp(T5 - m2),           \
            F6 = fexp(T6 - m2), F7 = fexp(T7 - m2);                               \
      float s2v = ((F0 + F1) + (F2 + F3)) + ((F4 + F5) + (F6 + F7));              \
      float r2 = frcp(s2v);                                                       \
      ZP[0] = F0 * r2; ZP[1] = F1 * r2; ZP[2] = F2 * r2; ZP[3] = F3 * r2;         \
      ZP[4] = F4 * r2; ZP[5] = F5 * r2; ZP[6] = F6 * r2; ZP[7] = F7 * r2;         \
      /* off-path: log-softmax output + stores (lanes 0-7) */                     \
      float mx = fmaxf(fmaxf(fmaxf(A0, A1), fmaxf(A2, A3v)),                      \
                       fmaxf(fmaxf(A4, A5), fmaxf(A6, A7)));                      \
      float E0 = fexp(A0 - mx), E1 = fexp(A1 - mx), E2 = fexp(A2 - mx),           \
            E3 = fexp(A3v - mx), E4 = fexp(A4 - mx), E5 = fexp(A5 - mx),          \
            E6 = fexp(A6 - mx), E7 = fexp(A7 - mx);                               \
      float se = ((E0 + E1) + (E2 + E3)) + ((E4 + E5) + (E6 + E7));               \
      float lse = mx + flog(se);                                                  \
      if (lane < 8) {                                                             \
        int l3 = lane & 3;                                                        \
        float ym = (l3 == 0) ? ZP[0] : (l3 == 1) ? ZP[1] : (l3 == 2) ? ZP[2] : ZP[3]; \
        outg[zoff + lane * TLEN + q_ + 1]  = ym;                                  \
        outg[qoff + lane * NSTEPS + sidx]  = a3m - lse;                           \
      }                                                                           \
      /* off-path: old-tap z-dot wzo.y(q_) — consumed at step q_+2 */             \
      {                                                                           \
        float z0 = fmaf(wzo[0], ZP[0], fmaf(wzo[1], ZP[1], 0.f));                 \
        float z1 = fmaf(wzo[2], ZP[2], fmaf(wzo[3], ZP[3], 0.f));                 \
        float z2 = fmaf(wzo[4], ZP[4], fmaf(wzo[5], ZP[5], 0.f));                 \
        float z3 = fmaf(wzo[6], ZP[6], fmaf(wzo[7], ZP[7], 0.f));                 \
        ZQ2n = (z0 + z1) + (z2 + z3);                                             \
      }                                                                           \
      /* gumbel prefetch for next step (slot order) */                            \
      {                                                                           \
        const char* gbase = (const char*)gls + (sidx + 1) * 32;                   \
        GA = *(const float4*)(gbase + pa_off);                                    \
        GB = *(const float4*)(gbase + pb_off);                                    \
      }                                                                           \
    }                                                                             \
    /* park x-part + old-z for step q_+1: ZQ2 == wzo.y(q_-1) here */              \
    {                                                                             \
      float xp = ldot8(&xcol[q_ + tap][0], wxr);                                  \
      XZ = xp + __shfl_down(xp, 32) + b0r + ZQ2;                                  \
      ZQ2 = ZQ2n;                                                                 \
    }                                                                             \
  }

__global__ __launch_bounds__(64, 1)
void regime_scan_kernel(const float* __restrict__ xg,
                        const float* __restrict__ tempg,
                        const float* __restrict__ ug,
                        const float* __restrict__ w0g,
                        const float* __restrict__ b0g,
                        const float* __restrict__ w1g,
                        const float* __restrict__ b1g,
                        const float* __restrict__ w2g,
                        const float* __restrict__ b2g,
                        const float* __restrict__ w3g,
                        const float* __restrict__ b3g,
                        float* __restrict__ outg)
{
    __shared__ __align__(16) float xcol[527][8];           // 16.9 KB
    __shared__ __align__(16) float gls[(NSTEPS + 1) * NK]; // 15.9 KB (+pad row)
    __shared__ __align__(16) float bc0[64], bc1[64], bc2[64];

    const int lane = threadIdx.x;
    const int b    = blockIdx.x;
    const int c    = lane & 31;
    const int o3   = lane & 7;
    const int tap  = (lane < 32) ? 1 : 0;
    const int p4   = (lane & 4);           // 4*parity: 0 or 4
    const int pa_off = (p4 ? 16 : 0);      // gumbel slot-order byte offsets
    const int pb_off = 16 - pa_off;

    // ---- per-lane weights (z-weights in DPP slot order: slot k <-> channel k^4p) ----
    float wzn[8], wzo[8];
    #pragma unroll
    for (int k = 0; k < 8; ++k) {
        int ch = k ^ p4;
        wzn[k] = w0g[c * 32 + (8 + ch) * 2 + 1];
        wzo[k] = w0g[c * 32 + (8 + ch) * 2 + 0];
    }
    float wxr[8];
    #pragma unroll
    for (int d = 0; d < 8; ++d) wxr[d] = w0g[c * 32 + d * 2 + tap];
    float w1r[32], w2r[32], w3r[32];
    #pragma unroll
    for (int i = 0; i < 32; ++i) {
        w1r[i] = w1g[c * 64 + i * 2 + tap];
        w2r[i] = w2g[c * 64 + i * 2 + tap];
        w3r[i] = w3g[o3 * 64 + i * 2 + tap];
    }
    const float b0r  = b0g[c];
    const float b1r  = b1g[c];
    const float b2r  = b2g[c];
    const float b3r  = b3g[o3];
    const float tinv = frcp(tempg[0]);

    // ---- prologue: x columns ----
    if (lane < 15) {
        #pragma unroll
        for (int d = 0; d < ND; ++d) xcol[lane][d] = 0.f;
    }
    const float* xb = xg + b * (ND * TLEN);
    for (int t = lane; t < TLEN; t += 64) {
        #pragma unroll
        for (int d = 0; d < ND; ++d) xcol[15 + t][d] = xb[d * TLEN + t];
    }
    // ---- prologue: Gumbel noise ----
    for (int idx = lane; idx < NSTEPS * NK; idx += 64) {
        int s = idx >> 3, k = idx & 7;
        float uu = ug[s * (NB * NK) + b * NK + k];
        gls[idx] = -flog(-flog(uu + 1e-10f) + 1e-10f);
    }
    // ---- z_all[:, :, 0:16] = 0 ----
    const int zoff = b * (NK * TLEN);
    const int qoff = NB * NK * TLEN + b * (NK * NSTEPS);
    for (int idx = lane; idx < NK * 16; idx += 64) {
        outg[zoff + (idx >> 4) * TLEN + (idx & 15)] = 0.f;
    }

    // ---- state ----
    float zA[8], zB[8];
    #pragma unroll
    for (int k = 0; k < 8; ++k) { zA[k] = 0.f; zB[k] = 0.f; }
    float P1[2] = { b1r, b1r };
    float P2[4] = { b2r, b2r, b2r, b2r };
    float P3[8];
    #pragma unroll
    for (int k = 0; k < 8; ++k) P3[k] = b3r;
    float ZQ2 = 0.f, ZQ2n = 0.f;
    float4 GA, GB;
    float XZ;
    {
        float xp = ldot8(&xcol[tap][0], wxr);
        XZ = xp + __shfl_down(xp, 32) + b0r;   // old-tap z = 0
    }

    // ---- warmup q=1..14 ----
    #pragma unroll
    for (int q = 1; q <= 14; ++q) STEP(q, q & 1, q & 3, q & 7, zA, zB, 0);

    // prefetch gumbel for sidx=0
    {
        const char* gbase = (const char*)gls;
        GA = *(const float4*)(gbase + pa_off);
        GB = *(const float4*)(gbase + pb_off);
    }

    // ---- main loop q=15..510, unrolled by 8 ----
    for (int qb = 15; qb <= 503; qb += 8) {
        #pragma unroll
        for (int u = 0; u < 8; u += 2) {
            STEP(qb + u,     (15 + u) & 1, (15 + u) & 3, (15 + u) & 7, zA, zB, 1);
            STEP(qb + u + 1, (16 + u) & 1, (16 + u) & 3, (16 + u) & 7, zB, zA, 1);
        }
    }
}

extern "C" void kernel_launch(void* const* d_in, const int* in_sizes, int n_in,
                              void* d_out, int out_size, void* d_ws, size_t ws_size,
                              hipStream_t stream) {
    (void)in_sizes; (void)n_in; (void)out_size; (void)d_ws; (void)ws_size;
    regime_scan_kernel<<<dim3(NB), dim3(64), 0, stream>>>(
        (const float*)d_in[0],   // x
        (const float*)d_in[1],   // temp
        (const float*)d_in[2],   // u
        (const float*)d_in[3],   // w0
        (const float*)d_in[4],   // b0
        (const float*)d_in[5],   // w1
        (const float*)d_in[6],   // b1
        (const float*)d_in[7],   // w2
        (const float*)d_in[8],   // b2
        (const float*)d_in[9],   // w3
        (const float*)d_in[10],  // b3
        (float*)d_out);
}

// Round 9
// 427.350 us; speedup vs baseline: 2.0656x; 1.2696x over previous
//
#include <hip/hip_runtime.h>

// Problem constants (from reference)
#define NB      128
#define ND      8
#define NK      8
#define TLEN    512
#define NSTEPS  496
#define QMAX    510

__device__ __forceinline__ float fexp(float x) { return __expf(x); }
__device__ __forceinline__ float flog(float x) { return __logf(x); }
__device__ __forceinline__ float frcp(float x) { return __builtin_amdgcn_rcpf(x); }
__device__ __forceinline__ float elur(float x) { return x > 0.f ? x : fexp(x) - 1.f; }

// DPP helpers. Data is replicated every 8 lanes (value = f(lane&7)), so within a
// 16-lane row: quad_perm 0xB1 = lane^1, 0x4E = lane^2, row_ror:4 acts as lane^4.
#define DPP_QP0(v)  __int_as_float(__builtin_amdgcn_mov_dpp(__float_as_int(v), 0x00, 0xF, 0xF, false))
#define DPP_QP1(v)  __int_as_float(__builtin_amdgcn_mov_dpp(__float_as_int(v), 0x55, 0xF, 0xF, false))
#define DPP_QP2(v)  __int_as_float(__builtin_amdgcn_mov_dpp(__float_as_int(v), 0xAA, 0xF, 0xF, false))
#define DPP_QP3(v)  __int_as_float(__builtin_amdgcn_mov_dpp(__float_as_int(v), 0xFF, 0xF, 0xF, false))
#define DPP_ROR4(v) __int_as_float(__builtin_amdgcn_mov_dpp(__float_as_int(v), 0x124, 0xF, 0xF, false))
#define DPP_X1(v)   __int_as_float(__builtin_amdgcn_mov_dpp(__float_as_int(v), 0xB1, 0xF, 0xF, false))
#define DPP_X2(v)   __int_as_float(__builtin_amdgcn_mov_dpp(__float_as_int(v), 0x4E, 0xF, 0xF, false))

// 8-group reductions (commutative -> all lanes end bitwise-identical)
#define RED8_MAX(m) { m = fmaxf(m, DPP_X1(m)); m = fmaxf(m, DPP_X2(m)); m = fmaxf(m, DPP_ROR4(m)); }
#define RED8_SUM(s) { s = s + DPP_X1(s); s = s + DPP_X2(s); s = s + DPP_ROR4(s); }

// dual 16-term dot (new+old tap weights) over 16 floats of LDS (4x b128 reads)
__device__ __forceinline__ void ldot16x2(const float* p, const float* wn, const float* wo,
                                         float& dn, float& dd) {
    const float4* q4 = (const float4*)p;
    float n0 = 0.f, n1 = 0.f, o0 = 0.f, o1 = 0.f;
    #pragma unroll
    for (int i = 0; i < 4; ++i) {
        float4 v = q4[i];
        n0 = fmaf(wn[4*i+0], v.x, n0);
        n1 = fmaf(wn[4*i+1], v.y, n1);
        o0 = fmaf(wo[4*i+0], v.x, o0);
        o1 = fmaf(wo[4*i+1], v.y, o1);
        n0 = fmaf(wn[4*i+2], v.z, n0);
        n1 = fmaf(wn[4*i+3], v.w, n1);
        o0 = fmaf(wo[4*i+2], v.z, o0);
        o1 = fmaf(wo[4*i+3], v.w, o1);
    }
    dn = n0 + n1;
    dd = o0 + o1;
}

__device__ __forceinline__ float ldot8(const float* p, const float* w) {
    const float4* q4 = (const float4*)p;
    float4 a = q4[0], b = q4[1];
    float s0 = fmaf(w[0], a.x, fmaf(w[1], a.y, 0.f));
    float s1 = fmaf(w[2], a.z, fmaf(w[3], a.w, 0.f));
    float s2 = fmaf(w[4], b.x, fmaf(w[5], b.y, 0.f));
    float s3 = fmaf(w[6], b.z, fmaf(w[7], b.w, 0.f));
    return (s0 + s1) + (s2 + s3);
}

// One scan step. Lanes = 32 channels x 2 K-halves. ZP = y(q-2) slots (overwritten
// with y(q)), ZC = y(q-1). Slot k holds channel k^4p, p = (lane>>2)&1.
// P-pipes: old-tap dot computed at q, consumed at q+d (d = 2/4/8).
// ZQ2 at step tail == wzo.y(q-1) -> layer-0 old tap for step q+1.
#define STEP(qv, S1, S2, S3, ZP, ZC, DO_OUT)                                      \
  {                                                                               \
    const int q_ = (qv);                                                          \
    float g_own = 0.f;                                                            \
    if (DO_OUT) g_own = gls[(q_ - 15) * NK + o3];  /* hoisted, latency hidden */  \
    /* layer 0: new-tap z-dot on critical path (old tap folded into XZ) */        \
    float _z0 = fmaf(wzn[0], ZC[0], 0.f);                                         \
    float _z1 = fmaf(wzn[1], ZC[1], 0.f);                                         \
    float _z2 = fmaf(wzn[2], ZC[2], 0.f);                                         \
    float _z3 = fmaf(wzn[3], ZC[3], 0.f);                                         \
    _z0 = fmaf(wzn[4], ZC[4], _z0);                                               \
    _z1 = fmaf(wzn[5], ZC[5], _z1);                                               \
    _z2 = fmaf(wzn[6], ZC[6], _z2);                                               \
    _z3 = fmaf(wzn[7], ZC[7], _z3);                                               \
    float o0v = elur(XZ + ((_z0 + _z1) + (_z2 + _z3)));                           \
    bc0[lane] = o0v;                                                              \
    /* layer 1 */                                                                 \
    float n1, d1o;                                                                \
    ldot16x2(bc0 + hoff, w1n, w1o, n1, d1o);                                      \
    float o1v = elur((n1 + __shfl_xor(n1, 32)) + P1[S1]);                         \
    P1[S1] = b1r + (d1o + __shfl_xor(d1o, 32));                                   \
    bc1[lane] = o1v;                                                              \
    /* layer 2 */                                                                 \
    float n2, d2o;                                                                \
    ldot16x2(bc1 + hoff, w2n, w2o, n2, d2o);                                      \
    float o2v = elur((n2 + __shfl_xor(n2, 32)) + P2[S2]);                         \
    P2[S2] = b2r + (d2o + __shfl_xor(d2o, 32));                                   \
    bc2[lane] = o2v;                                                              \
    /* layer 3 */                                                                 \
    float n3, d3o;                                                                \
    ldot16x2(bc2 + hoff, w3n, w3o, n3, d3o);                                      \
    float a3m = elur((n3 + __shfl_xor(n3, 32)) + P3[S3]);                         \
    P3[S3] = b3r + (d3o + __shfl_xor(d3o, 32));                                   \
    if (DO_OUT) {                                                                 \
      /* gumbel-softmax: per-lane own-channel exp + DPP reduce/broadcast */       \
      float T = (a3m + g_own) * tinv;                                             \
      float m2 = T; RED8_MAX(m2);                                                 \
      float F = fexp(T - m2);                                                     \
      float S = F; RED8_SUM(S);                                                   \
      float r2 = frcp(S);                                                         \
      float _t = DPP_ROR4(F);                                                     \
      float F0 = DPP_QP0(F),  F1 = DPP_QP1(F),  F2 = DPP_QP2(F),                  \
            F3 = DPP_QP3(F);                                                      \
      float F4 = DPP_QP0(_t), F5 = DPP_QP1(_t), F6 = DPP_QP2(_t),                 \
            F7 = DPP_QP3(_t);                                                     \
      ZP[0] = F0 * r2; ZP[1] = F1 * r2; ZP[2] = F2 * r2; ZP[3] = F3 * r2;         \
      ZP[4] = F4 * r2; ZP[5] = F5 * r2; ZP[6] = F6 * r2; ZP[7] = F7 * r2;         \
      /* off-path: old-tap z-dot wzo.y(q_) — consumed at step q_+2 */             \
      {                                                                           \
        float z0 = fmaf(wzo[0], ZP[0], fmaf(wzo[1], ZP[1], 0.f));                 \
        float z1 = fmaf(wzo[2], ZP[2], fmaf(wzo[3], ZP[3], 0.f));                 \
        float z2 = fmaf(wzo[4], ZP[4], fmaf(wzo[5], ZP[5], 0.f));                 \
        float z3 = fmaf(wzo[6], ZP[6], fmaf(wzo[7], ZP[7], 0.f));                 \
        ZQ2n = (z0 + z1) + (z2 + z3);                                             \
      }                                                                           \
      /* off-path: log-softmax output (single exp + DPP reductions) */            \
      float mx = a3m; RED8_MAX(mx);                                               \
      float e = fexp(a3m - mx);                                                   \
      float se = e; RED8_SUM(se);                                                 \
      float lse = mx + flog(se);                                                  \
      if (lane < 8) {                                                             \
        outg[zoff + lane * TLEN + q_ + 1]       = F * r2;                         \
        outg[qoff + lane * NSTEPS + (q_ - 15)]  = a3m - lse;                      \
      }                                                                           \
    }                                                                             \
    /* park x-part + old-z for step q_+1: ZQ2 == wzo.y(q_-1) here */              \
    {                                                                             \
      float xp = ldot8(&xcol[q_ + tap][0], wxr);                                  \
      XZ = (xp + __shfl_xor(xp, 32)) + b0r + ZQ2;                                 \
      ZQ2 = ZQ2n;                                                                 \
    }                                                                             \
  }

__global__ __launch_bounds__(64, 1)
void regime_scan_kernel(const float* __restrict__ xg,
                        const float* __restrict__ tempg,
                        const float* __restrict__ ug,
                        const float* __restrict__ w0g,
                        const float* __restrict__ b0g,
                        const float* __restrict__ w1g,
                        const float* __restrict__ b1g,
                        const float* __restrict__ w2g,
                        const float* __restrict__ b2g,
                        const float* __restrict__ w3g,
                        const float* __restrict__ b3g,
                        float* __restrict__ outg)
{
    __shared__ __align__(16) float xcol[527][8];     // 16.9 KB
    __shared__ __align__(16) float gls[NSTEPS * NK]; // 15.9 KB
    __shared__ __align__(16) float bc0[64], bc1[64], bc2[64];

    const int lane = threadIdx.x;
    const int b    = blockIdx.x;
    const int c    = lane & 31;            // channel owned
    const int o3   = lane & 7;             // layer-3 channel owned
    const int half = lane >> 5;            // K-half owned (layers 1-3)
    const int hoff = half << 4;            // float offset into bc
    const int tap  = (lane < 32) ? 1 : 0;  // x-park tap role
    const int p4   = (lane & 4);           // slot-order parity*4

    // ---- per-lane weights ----
    float wzn[8], wzo[8];                  // layer0 z weights, slot order
    #pragma unroll
    for (int k = 0; k < 8; ++k) {
        int ch = k ^ p4;
        wzn[k] = w0g[c * 32 + (8 + ch) * 2 + 1];
        wzo[k] = w0g[c * 32 + (8 + ch) * 2 + 0];
    }
    float wxr[8];
    #pragma unroll
    for (int d = 0; d < 8; ++d) wxr[d] = w0g[c * 32 + d * 2 + tap];
    float w1n[16], w1o[16], w2n[16], w2o[16], w3n[16], w3o[16];
    #pragma unroll
    for (int i = 0; i < 16; ++i) {
        int j = hoff + i;
        w1n[i] = w1g[c * 64 + j * 2 + 1];
        w1o[i] = w1g[c * 64 + j * 2 + 0];
        w2n[i] = w2g[c * 64 + j * 2 + 1];
        w2o[i] = w2g[c * 64 + j * 2 + 0];
        w3n[i] = w3g[o3 * 64 + j * 2 + 1];
        w3o[i] = w3g[o3 * 64 + j * 2 + 0];
    }
    const float b0r  = b0g[c];
    const float b1r  = b1g[c];
    const float b2r  = b2g[c];
    const float b3r  = b3g[o3];
    const float tinv = frcp(tempg[0]);

    // ---- prologue: x columns ----
    if (lane < 15) {
        #pragma unroll
        for (int d = 0; d < ND; ++d) xcol[lane][d] = 0.f;
    }
    const float* xb = xg + b * (ND * TLEN);
    for (int t = lane; t < TLEN; t += 64) {
        #pragma unroll
        for (int d = 0; d < ND; ++d) xcol[15 + t][d] = xb[d * TLEN + t];
    }
    // ---- prologue: Gumbel noise ----
    for (int idx = lane; idx < NSTEPS * NK; idx += 64) {
        int s = idx >> 3, k = idx & 7;
        float uu = ug[s * (NB * NK) + b * NK + k];
        gls[idx] = -flog(-flog(uu + 1e-10f) + 1e-10f);
    }
    // ---- z_all[:, :, 0:16] = 0 ----
    const int zoff = b * (NK * TLEN);
    const int qoff = NB * NK * TLEN + b * (NK * NSTEPS);
    for (int idx = lane; idx < NK * 16; idx += 64) {
        outg[zoff + (idx >> 4) * TLEN + (idx & 15)] = 0.f;
    }

    // ---- state ----
    float zA[8], zB[8];
    #pragma unroll
    for (int k = 0; k < 8; ++k) { zA[k] = 0.f; zB[k] = 0.f; }
    float P1[2] = { b1r, b1r };
    float P2[4] = { b2r, b2r, b2r, b2r };
    float P3[8];
    #pragma unroll
    for (int k = 0; k < 8; ++k) P3[k] = b3r;
    float ZQ2 = 0.f, ZQ2n = 0.f;
    float XZ;
    {
        float xp = ldot8(&xcol[tap][0], wxr);
        XZ = (xp + __shfl_xor(xp, 32)) + b0r;   // old-tap z = 0
    }

    // ---- warmup q=1..14 ----
    #pragma unroll
    for (int q = 1; q <= 14; ++q) STEP(q, q & 1, q & 3, q & 7, zA, zB, 0);

    // ---- main loop q=15..510, unrolled by 8; z double-buffer by parity ----
    for (int qb = 15; qb <= 503; qb += 8) {
        #pragma unroll
        for (int u = 0; u < 8; u += 2) {
            STEP(qb + u,     (15 + u) & 1, (15 + u) & 3, (15 + u) & 7, zA, zB, 1);
            STEP(qb + u + 1, (16 + u) & 1, (16 + u) & 3, (16 + u) & 7, zB, zA, 1);
        }
    }
}

extern "C" void kernel_launch(void* const* d_in, const int* in_sizes, int n_in,
                              void* d_out, int out_size, void* d_ws, size_t ws_size,
                              hipStream_t stream) {
    (void)in_sizes; (void)n_in; (void)out_size; (void)d_ws; (void)ws_size;
    regime_scan_kernel<<<dim3(NB), dim3(64), 0, stream>>>(
        (const float*)d_in[0],   // x
        (const float*)d_in[1],   // temp
        (const float*)d_in[2],   // u
        (const float*)d_in[3],   // w0
        (const float*)d_in[4],   // b0
        (const float*)d_in[5],   // w1
        (const float*)d_in[6],   // b1
        (const float*)d_in[7],   // w2
        (const float*)d_in[8],   // b2
        (const float*)d_in[9],   // w3
        (const float*)d_in[10],  // b3
        (float*)d_out);
}